// Round 6
// baseline (131.410 us; speedup 1.0000x reference)
//
#include <hip/hip_runtime.h>
#include <hip/hip_bf16.h>

typedef short short8 __attribute__((ext_vector_type(8)));
typedef float f32x4 __attribute__((ext_vector_type(4)));

#define NB 4096   // batch rows
#define KZ 2048   // concat K (IN + OUT)
#define NG 1024   // per-gate output cols
#define NKS 32    // macro K-steps of 64 (each does wh and wl sharing A)

__device__ __forceinline__ unsigned short f2bf(float f) {
  unsigned int u = __float_as_uint(f);
  u += 0x7FFFu + ((u >> 16) & 1u);   // RNE
  return (unsigned short)(u >> 16);
}
__device__ __forceinline__ float bf2f(unsigned short s) {
  return __uint_as_float(((unsigned int)s) << 16);
}
__device__ __forceinline__ void gload_lds16(const void* g, void* l) {
  __builtin_amdgcn_global_load_lds(
      (__attribute__((address_space(1))) void*)g,
      (__attribute__((address_space(3))) void*)l, 16, 0, 0);
}
__device__ __forceinline__ float sigm(float x) { return 1.f / (1.f + __expf(-x)); }
__device__ __forceinline__ float tanh_fast(float x) {
  float e = __expf(-2.f * fabsf(x));
  float r = (1.f - e) / (1.f + e);
  return copysignf(r, x);
}

// ---- concat([x,h]) -> bf16 zh [4096][2048] ----
__global__ void zsplit_kernel(const float* __restrict__ x, const float* __restrict__ h,
                              unsigned short* __restrict__ zh) {
  int idx = blockIdx.x * 256 + threadIdx.x;
  int e = idx << 2;
  int r = e >> 11;
  int k = e & (KZ - 1);
  const float* src = (k < 1024) ? (x + ((size_t)r << 10) + k)
                                : (h + ((size_t)r << 10) + (k - 1024));
  float4 v = *reinterpret_cast<const float4*>(src);
  float vf[4] = {v.x, v.y, v.z, v.w};
  unsigned short hh[4];
#pragma unroll
  for (int j = 0; j < 4; ++j) hh[j] = f2bf(vf[j]);
  uint2 H = make_uint2((unsigned)hh[0] | ((unsigned)hh[1] << 16),
                       (unsigned)hh[2] | ((unsigned)hh[3] << 16));
  *reinterpret_cast<uint2*>(zh + e) = H;
}

// ---- transpose + hi/lo split weights into gate-interleaved packed rows ----
// p = (n>>6)<<8 | ((n>>4)&3)<<6 | g<<4 | (n&15)
__global__ void wsplit_kernel(const float* __restrict__ w0, const float* __restrict__ w1,
                              const float* __restrict__ w2, const float* __restrict__ w3,
                              unsigned short* __restrict__ wh, unsigned short* __restrict__ wl) {
  __shared__ float tile[32][33];
  int g = blockIdx.z;
  const float* w = (g == 0) ? w0 : (g == 1) ? w1 : (g == 2) ? w2 : w3;
  int k0 = blockIdx.x << 5;
  int n0 = blockIdx.y << 5;
  int t = threadIdx.x;
  int rk = t >> 3, q = t & 7;
  float4 v = *reinterpret_cast<const float4*>(w + (size_t)(k0 + rk) * NG + n0 + (q << 2));
  tile[rk][(q << 2) + 0] = v.x;
  tile[rk][(q << 2) + 1] = v.y;
  tile[rk][(q << 2) + 2] = v.z;
  tile[rk][(q << 2) + 3] = v.w;
  __syncthreads();
  int n = t >> 3, kq = t & 7;
  unsigned short hs[4], ls[4];
#pragma unroll
  for (int j = 0; j < 4; ++j) {
    float f = tile[(kq << 2) + j][n];
    unsigned short hi = f2bf(f);
    unsigned short lo = f2bf(f - bf2f(hi));
    hs[j] = hi; ls[j] = lo;
  }
  int nn = n0 + n;
  int p = ((nn >> 6) << 8) | (((nn >> 4) & 3) << 6) | (g << 4) | (nn & 15);
  size_t o = (size_t)p * KZ + k0 + (kq << 2);
  uint2 H = make_uint2((unsigned)hs[0] | ((unsigned)hs[1] << 16),
                       (unsigned)hs[2] | ((unsigned)hs[3] << 16));
  uint2 L = make_uint2((unsigned)ls[0] | ((unsigned)ls[1] << 16),
                       (unsigned)ls[2] | ((unsigned)ls[3] << 16));
  *reinterpret_cast<uint2*>(wh + o) = H;
  *reinterpret_cast<uint2*>(wl + o) = L;
}

#define MFMA(a, b, c) __builtin_amdgcn_mfma_f32_16x16x32_bf16((a), (b), (c), 0, 0, 0)
#define ABAR() asm volatile("s_barrier" ::: "memory")
#define LGKM(N) asm volatile("s_waitcnt lgkmcnt(" #N ")" ::: "memory")
#define VMC0() asm volatile("s_waitcnt vmcnt(0)" ::: "memory")
#define SB() __builtin_amdgcn_sched_barrier(0)
#define PRIO1() __builtin_amdgcn_s_setprio(1)
#define PRIO0() __builtin_amdgcn_s_setprio(0)

// ---- 256x256 counted-lgkm pipelined fused 4-gate GEMM + LSTM epilogue ----
// 8 waves (2M x 4N); macro K-step BK=64; A shared in regs across wh & wl tiles.
// 2 barriers per macro; ds-reads issued one MFMA-group ahead (counted lgkm).
__global__ __launch_bounds__(512, 2) void lstm_gemm256_kernel(
    const unsigned short* __restrict__ zh,
    const unsigned short* __restrict__ wh, const unsigned short* __restrict__ wl,
    const float* __restrict__ c_in, const float* __restrict__ bf_,
    const float* __restrict__ bi_, const float* __restrict__ bc_,
    const float* __restrict__ bo_, float* __restrict__ out) {
  __shared__ unsigned short As[2 * 16384];   // 2 dbuf x 256 rows x 64 k = 64 KB
  __shared__ unsigned short Bh[16384];       // wh tile, 32 KB
  __shared__ unsigned short Bl[16384];       // wl tile, 32 KB
  const int t = threadIdx.x;
  const int lane = t & 63;
  const int wid = t >> 6;
  const int wr = wid >> 2;
  const int wc = wid & 3;
  const int l15 = lane & 15;
  const int l4 = lane >> 4;

  const int bid = blockIdx.x;
  const int swz = ((bid & 7) << 5) + (bid >> 3);   // XCD-aware bijective
  const int bx = swz & 15;
  const int by = swz >> 4;
  const int brow0 = by << 8;
  const int pcol0 = bx << 8;

  char* AsB = (char*)As;
  char* BhB = (char*)Bh;
  char* BlB = (char*)Bl;

  int aoff[2], boff[2];
#pragma unroll
  for (int j = 0; j < 2; ++j) {
    int row = (j << 6) + (t >> 3);
    int sl = (t & 7) ^ (row & 7);
    aoff[j] = (brow0 + row) * KZ + (sl << 3);
    boff[j] = (pcol0 + row) * KZ + (sl << 3);
  }
  const int ldsw = wid << 10;

  // hx: 0,1 = A halves (dbuf by (ks)&1); 2,3 = wh halves; 4,5 = wl halves
  auto STAGE = [&](int s, int hx) {
    if (s >= NKS) return;
    const int kk = s << 6;
    if (hx < 2) {
      const int lb = ((s & 1) << 15) + (hx << 14);
#pragma unroll
      for (int j = 0; j < 2; ++j)
        gload_lds16(zh + aoff[j] + hx * (128 * KZ) + kk, AsB + lb + (j << 13) + ldsw);
    } else if (hx < 4) {
      const int hq = hx - 2;
#pragma unroll
      for (int j = 0; j < 2; ++j)
        gload_lds16(wh + boff[j] + hq * (128 * KZ) + kk, BhB + (hq << 14) + (j << 13) + ldsw);
    } else {
      const int hq = hx - 4;
#pragma unroll
      for (int j = 0; j < 2; ++j)
        gload_lds16(wl + boff[j] + hq * (128 * KZ) + kk, BlB + (hq << 14) + (j << 13) + ldsw);
    }
  };

  f32x4 acc[8][4];
#pragma unroll
  for (int m = 0; m < 8; ++m)
#pragma unroll
    for (int n = 0; n < 4; ++n) acc[m][n] = (f32x4){0.f, 0.f, 0.f, 0.f};

  const int rx = l15 & 7;
  const int sx0 = (l4 ^ rx) << 4;
  const int sx1 = ((4 + l4) ^ rx) << 4;
  const int aB = l15 << 7;
  const int bB = ((wc & 1) << 13) + (l15 << 7);
  const int aW = wr << 14;
  const int bW = (wc >> 1) << 14;

  short8 aL0[4], aH0[4], aL1[4], aH1[4], vbh0[4], vbh1[4], vbl0[4], vbl1[4];

  // prologue: stage tile0 fully; land; barrier
  STAGE(0, 0); STAGE(0, 1); STAGE(0, 2); STAGE(0, 3); STAGE(0, 4); STAGE(0, 5);
  VMC0();
  ABAR();

  for (int ks = 0; ks < NKS; ++ks) {
    const int abase = ((ks & 1) << 15) + aW;

    // ---- R1: aL0 + bh0 (8 reads) ----
#pragma unroll
    for (int m = 0; m < 4; ++m)
      aL0[m] = *reinterpret_cast<const short8*>(AsB + abase + aB + (m << 11) + sx0);
#pragma unroll
    for (int n = 0; n < 4; ++n)
      vbh0[n] = *reinterpret_cast<const short8*>(BhB + bW + bB + (n << 11) + sx0);
    SB();
    // ---- R2: bl0 (4) ----
#pragma unroll
    for (int n = 0; n < 4; ++n)
      vbl0[n] = *reinterpret_cast<const short8*>(BlB + bW + bB + (n << 11) + sx0);
    SB();
    STAGE(ks + 1, 0);
    LGKM(4); SB();                 // R1 done (R2 outstanding)
    PRIO1();
#pragma unroll
    for (int m = 0; m < 4; ++m)
#pragma unroll
      for (int n = 0; n < 4; ++n) acc[m][n] = MFMA(aL0[m], vbh0[n], acc[m][n]);   // G1
    PRIO0();

    // ---- R3: aH0 (4) ----
#pragma unroll
    for (int m = 0; m < 4; ++m)
      aH0[m] = *reinterpret_cast<const short8*>(AsB + abase + aB + ((m + 4) << 11) + sx0);
    SB();
    STAGE(ks + 1, 1);
    LGKM(4); SB();                 // R2 done (R3 outstanding)
    PRIO1();
#pragma unroll
    for (int m = 0; m < 4; ++m)
#pragma unroll
      for (int n = 0; n < 4; ++n) acc[m][n] = MFMA(aL0[m], vbl0[n], acc[m][n]);   // G2
    PRIO0();

    // ---- R5: aL1 + bh1 (8) ----
#pragma unroll
    for (int m = 0; m < 4; ++m)
      aL1[m] = *reinterpret_cast<const short8*>(AsB + abase + aB + (m << 11) + sx1);
#pragma unroll
    for (int n = 0; n < 4; ++n)
      vbh1[n] = *reinterpret_cast<const short8*>(BhB + bW + bB + (n << 11) + sx1);
    SB();
    LGKM(8); SB();                 // R3 done (R5 outstanding)
    PRIO1();
#pragma unroll
    for (int m = 0; m < 4; ++m)
#pragma unroll
      for (int n = 0; n < 4; ++n) acc[m + 4][n] = MFMA(aH0[m], vbh0[n], acc[m + 4][n]); // G3
    PRIO0();

    // ---- R6: bl1 (4) ----
#pragma unroll
    for (int n = 0; n < 4; ++n)
      vbl1[n] = *reinterpret_cast<const short8*>(BlB + bW + bB + (n << 11) + sx1);
    SB();
    PRIO1();
#pragma unroll
    for (int m = 0; m < 4; ++m)
#pragma unroll
      for (int n = 0; n < 4; ++n) acc[m + 4][n] = MFMA(aH0[m], vbl0[n], acc[m + 4][n]); // G4
    PRIO0();

    LGKM(0); SB();                 // all B reads of this tile complete
    ABAR();                        // BAR12: WAR-safe to overwrite Bh/Bl
    STAGE(ks + 1, 2); STAGE(ks + 1, 3); STAGE(ks + 1, 4); STAGE(ks + 1, 5);
    PRIO1();
#pragma unroll
    for (int m = 0; m < 4; ++m)
#pragma unroll
      for (int n = 0; n < 4; ++n) acc[m][n] = MFMA(aL1[m], vbh1[n], acc[m][n]);   // G5
    PRIO0();

    // ---- R7: aH1 (4) ----
#pragma unroll
    for (int m = 0; m < 4; ++m)
      aH1[m] = *reinterpret_cast<const short8*>(AsB + abase + aB + ((m + 4) << 11) + sx1);
    SB();
    PRIO1();
#pragma unroll
    for (int m = 0; m < 4; ++m)
#pragma unroll
      for (int n = 0; n < 4; ++n) acc[m][n] = MFMA(aL1[m], vbl1[n], acc[m][n]);   // G6
    PRIO0();

    LGKM(0); SB();                 // R7 done
    PRIO1();
#pragma unroll
    for (int m = 0; m < 4; ++m)
#pragma unroll
      for (int n = 0; n < 4; ++n) acc[m + 4][n] = MFMA(aH1[m], vbh1[n], acc[m + 4][n]); // G7
#pragma unroll
    for (int m = 0; m < 4; ++m)
#pragma unroll
      for (int n = 0; n < 4; ++n) acc[m + 4][n] = MFMA(aH1[m], vbl1[n], acc[m + 4][n]); // G8
    PRIO0();

    VMC0(); SB();                  // all 12 staging gloads for tile ks+1 landed
    ABAR();                        // BAR3: global visibility + A-dbuf WAR
  }

  // ---- epilogue: lane holds all 4 gates (col-frags) for one column ----
  const int ng = (bx << 6) + (wc << 4) + l15;
  const float vbf = bf_[ng], vbi = bi_[ng], vbc = bc_[ng], vbo = bo_[ng];
#pragma unroll
  for (int m = 0; m < 8; ++m) {
#pragma unroll
    for (int r = 0; r < 4; ++r) {
      const int row = brow0 + (wr << 7) + (m << 4) + (l4 << 2) + r;
      const float fp = acc[m][0][r] + vbf;
      const float ip = acc[m][1][r] + vbi;
      const float gp = acc[m][2][r] + vbc;
      const float op = acc[m][3][r] + vbo;
      const float co = c_in[(size_t)row * NG + ng];
      const float cnew = co * sigm(fp) + sigm(ip) * tanh_fast(gp);
      out[(size_t)row * NG + ng] = tanh_fast(cnew) * sigm(op);
    }
  }
}

extern "C" void kernel_launch(void* const* d_in, const int* in_sizes, int n_in,
                              void* d_out, int out_size, void* d_ws, size_t ws_size,
                              hipStream_t stream) {
  const float* x   = (const float*)d_in[0];
  const float* h   = (const float*)d_in[1];
  const float* c   = (const float*)d_in[2];
  const float* w_f = (const float*)d_in[3];
  const float* b_f = (const float*)d_in[4];
  const float* w_i = (const float*)d_in[5];
  const float* b_i = (const float*)d_in[6];
  const float* w_c = (const float*)d_in[7];
  const float* b_c = (const float*)d_in[8];
  const float* w_o = (const float*)d_in[9];
  const float* b_o = (const float*)d_in[10];
  float* out = (float*)d_out;

  unsigned short* zh = (unsigned short*)d_ws;                 // 16 MB
  unsigned short* wh = zh + (size_t)NB * KZ;                  // 16 MB
  unsigned short* wl = wh + (size_t)KZ * 4096;                // 16 MB

  zsplit_kernel<<<(NB * KZ / 4) / 256, 256, 0, stream>>>(x, h, zh);
  wsplit_kernel<<<dim3(KZ / 32, NG / 32, 4), 256, 0, stream>>>(w_f, w_i, w_c, w_o, wh, wl);
  lstm_gemm256_kernel<<<256, 512, 0, stream>>>(zh, wh, wl, c,
                                               b_f, b_i, b_c, b_o, out);
}